// Round 2
// baseline (101.938 us; speedup 1.0000x reference)
//
#include <hip/hip_runtime.h>

// ScaledDotProductAttention B=8, L=2048, D=64, fp32 in/out.
//
// R15: split-K with LDS-resident fragments. Evidence: rocprof shows NO kernel
// dispatch above the ~41 us poison fills in either round => dur_us carries a
// ~52 us constant harness overhead; controllable kernel time was ~31 us (R13
// two-launch) and ~40 us (R14 fused, 1 block/CU + barrier-per-tile = exposed
// latency). This version removes both failure modes:
//   - attn_splitk: 512 blocks = b(8) x kg(8 key-slices of 256) x qc(8 query
//     chunks of 256). 512 thr = 8 waves, 2 blocks/CU (64 KB LDS), 4 waves/SIMD.
//     Each block converts its fp32 K/V slice -> f16 MFMA fragments in LDS ONCE
//     (prepass math verbatim), one barrier, then a ZERO-barrier hot loop:
//     wave owns 32 queries, walks 8 tiles of 32 keys straight from LDS.
//       - S^T = K*Q^T via mfma_f32_16x16x32_f16 (0.125*log2e folded into Q).
//       - p = exp2(s); packed half4 IS the B-frag of mfma_f32_16x16x16f16.
//       - PV: O^T += V^T A-frags x P^T. V frags stored ks-paired so one
//         ds_read_b128 yields both 16x16x16 A-frags.
//     Per-kg partials (O 64 f32/query + l) to workspace.
//   - combine: 1024 blocks x 256 thr; sums 8 kg partials, divides, stores.
// Numerics identical to the verified R13 kernel (8-way key split, fp32
// partials, f16 p) => absmax expectation unchanged.
// Fallback: proven R3 kernel if ws too small.

#define B_ 8
#define L_ 2048
#define D_ 64

typedef _Float16 half8_t __attribute__((ext_vector_type(8)));
typedef _Float16 half4_t __attribute__((ext_vector_type(4)));
typedef float f32x4 __attribute__((ext_vector_type(4)));

#define SCALE_LOG2E 0.1803368801111244f   // 0.125 * log2(e)

// ---------------------------------------------------------- attn_splitk ----
__global__ __launch_bounds__(512, 4) void attn_splitk(
    const float* __restrict__ Q, const float* __restrict__ K,
    const float* __restrict__ V, float* __restrict__ PW,
    float* __restrict__ LW)
{
    // K frags: 8 tiles x 4 planes x 512 halfs; V frags: 8 x 4 x 512 (ks-paired)
    __shared__ __align__(16) _Float16 KL[16384];   // 32 KB
    __shared__ __align__(16) _Float16 VL[16384];   // 32 KB

    const int t    = threadIdx.x;
    const int wave = t >> 6;
    const int lane = t & 63;
    const int quad = lane >> 4;
    const int l15  = lane & 15;

    const int blk = blockIdx.x;
    const int b   = blk & 7;               // batch <-> XCD affinity
    const int kg  = (blk >> 3) & 7;        // key slice: 256 keys
    const int qc  = blk >> 6;              // query chunk: 256 queries

    const size_t boff = (size_t)b * L_ * D_;
    const int key0 = kg * 256;
    const int q0   = qc * 256 + wave * 32; // wave owns 32 queries

    // ---- Q B-frags from fp32, pre-scaled (issued before staging) ----------
    half8_t bq[2][2];
    #pragma unroll
    for (int qs = 0; qs < 2; ++qs) {
        const float* qp = Q + boff + (size_t)(q0 + qs * 16 + l15) * D_ + quad * 8;
        #pragma unroll
        for (int c = 0; c < 2; ++c) {
            const float4 f0 = *(const float4*)(qp + c * 32);
            const float4 f1 = *(const float4*)(qp + c * 32 + 4);
            bq[qs][c][0] = (_Float16)(f0.x * SCALE_LOG2E);
            bq[qs][c][1] = (_Float16)(f0.y * SCALE_LOG2E);
            bq[qs][c][2] = (_Float16)(f0.z * SCALE_LOG2E);
            bq[qs][c][3] = (_Float16)(f0.w * SCALE_LOG2E);
            bq[qs][c][4] = (_Float16)(f1.x * SCALE_LOG2E);
            bq[qs][c][5] = (_Float16)(f1.y * SCALE_LOG2E);
            bq[qs][c][6] = (_Float16)(f1.z * SCALE_LOG2E);
            bq[qs][c][7] = (_Float16)(f1.w * SCALE_LOG2E);
        }
    }

    // ---- stage K frags: 2048 jobs (prepass math, row base = key0) ---------
    #pragma unroll
    for (int i = 0; i < 4; ++i) {
        const int j  = i * 512 + t;
        const int kt = j >> 8, kj = j & 255;
        const int p  = kj >> 6, jl = kj & 63;
        const int jq = jl >> 4, jl15 = jl & 15;
        const int s = p >> 1, c = p & 1;
        const int row = key0 + kt * 32 + s * 16 + jl15;
        const float* kp = K + boff + (size_t)row * D_ + c * 32 + jq * 8;
        const float4 f0 = *(const float4*)kp;
        const float4 f1 = *(const float4*)(kp + 4);
        half8_t w;
        w[0] = (_Float16)f0.x; w[1] = (_Float16)f0.y;
        w[2] = (_Float16)f0.z; w[3] = (_Float16)f0.w;
        w[4] = (_Float16)f1.x; w[5] = (_Float16)f1.y;
        w[6] = (_Float16)f1.z; w[7] = (_Float16)f1.w;
        *(half8_t*)&KL[kt * 2048 + p * 512 + jl * 8] = w;
    }
    // ---- stage V frags: 4096 jobs; (d,ks) pair co-located per lane --------
    #pragma unroll
    for (int i = 0; i < 8; ++i) {
        const int j  = i * 512 + t;
        const int kt = j >> 9, kj = j & 511;
        const int p  = kj >> 6, jl = kj & 63;
        const int jq = jl >> 4, jl15 = jl & 15;
        const int d = p >> 1, ks = p & 1;
        const int row = key0 + kt * 32 + ks * 16 + jq * 4;
        const float* vp = V + boff + (size_t)row * D_ + d * 16 + jl15;
        half4_t a;
        a[0] = (_Float16)vp[0];
        a[1] = (_Float16)vp[D_];
        a[2] = (_Float16)vp[2 * D_];
        a[3] = (_Float16)vp[3 * D_];
        *(half4_t*)&VL[kt * 2048 + d * 512 + jl * 8 + ks * 4] = a;
    }
    __syncthreads();   // the ONLY barrier

    f32x4 ofr[2][4];
    #pragma unroll
    for (int qs = 0; qs < 2; ++qs)
        #pragma unroll
        for (int d = 0; d < 4; ++d)
            ofr[qs][d] = (f32x4){0.f, 0.f, 0.f, 0.f};
    float lacc[2] = {0.f, 0.f};

    // ---- hot loop: 8 tiles x 32 keys, pure LDS + registers ----------------
    #pragma unroll
    for (int kt = 0; kt < 8; ++kt) {
        const _Float16* Kt = &KL[kt * 2048];
        const _Float16* Vt = &VL[kt * 2048];
        half8_t bk[2][2];
        #pragma unroll
        for (int s = 0; s < 2; ++s)
            #pragma unroll
            for (int c = 0; c < 2; ++c)
                bk[s][c] = *(const half8_t*)&Kt[(s * 2 + c) * 512 + lane * 8];
        half4_t pv[2][2];
        #pragma unroll
        for (int ks = 0; ks < 2; ++ks)
            #pragma unroll
            for (int qs = 0; qs < 2; ++qs) {
                f32x4 acc = (f32x4){0.f, 0.f, 0.f, 0.f};
                acc = __builtin_amdgcn_mfma_f32_16x16x32_f16(bk[ks][0], bq[qs][0], acc, 0, 0, 0);
                acc = __builtin_amdgcn_mfma_f32_16x16x32_f16(bk[ks][1], bq[qs][1], acc, 0, 0, 0);
                const float p0 = __builtin_exp2f(acc[0]);
                const float p1 = __builtin_exp2f(acc[1]);
                const float p2 = __builtin_exp2f(acc[2]);
                const float p3 = __builtin_exp2f(acc[3]);
                lacc[qs] += (p0 + p1) + (p2 + p3);
                half4_t pw;
                pw[0] = (_Float16)p0; pw[1] = (_Float16)p1;
                pw[2] = (_Float16)p2; pw[3] = (_Float16)p3;
                pv[ks][qs] = pw;
            }
        #pragma unroll
        for (int d = 0; d < 4; ++d) {
            const half8_t av8 = *(const half8_t*)&Vt[d * 512 + lane * 8];
            const half4_t alo = __builtin_shufflevector(av8, av8, 0, 1, 2, 3);
            const half4_t ahi = __builtin_shufflevector(av8, av8, 4, 5, 6, 7);
            #pragma unroll
            for (int qs = 0; qs < 2; ++qs) {
                ofr[qs][d] = __builtin_amdgcn_mfma_f32_16x16x16f16(alo, pv[0][qs], ofr[qs][d], 0, 0, 0);
                ofr[qs][d] = __builtin_amdgcn_mfma_f32_16x16x16f16(ahi, pv[1][qs], ofr[qs][d], 0, 0, 0);
            }
        }
    }

    // ---- partials out: O^T frag scatter + l (quad-reduced) ----------------
    const size_t pbase = (size_t)(b * 8 + kg) * L_;
    #pragma unroll
    for (int qs = 0; qs < 2; ++qs) {
        float v = lacc[qs];
        v += __shfl_xor(v, 16, 64);
        v += __shfl_xor(v, 32, 64);
        const int q = q0 + qs * 16 + l15;
        float* pw = PW + (pbase + q) * D_;
        #pragma unroll
        for (int d = 0; d < 4; ++d) {
            float4 o;
            o.x = ofr[qs][d][0]; o.y = ofr[qs][d][1];
            o.z = ofr[qs][d][2]; o.w = ofr[qs][d][3];
            *(float4*)&pw[d * 16 + quad * 4] = o;
        }
        if (quad == 0) LW[pbase + q] = v;
    }
}

// -------------------------------------------------------------- combine ----
__global__ __launch_bounds__(256) void combine(
    const float* __restrict__ PW, const float* __restrict__ LW,
    float* __restrict__ O)
{
    const int blk = blockIdx.x;
    const int b  = blk & 7;                 // batch <-> XCD affinity
    const int qi = blk >> 3;                // 0..127 (16 queries each)
    const int t  = threadIdx.x;
    const int lq = t >> 4;                  // 0..15
    const int c4 = t & 15;                  // 0..15 (float4 chunk)
    const int q  = qi * 16 + lq;

    f32x4 s = (f32x4){0.f, 0.f, 0.f, 0.f};
    float l = 0.f;
    #pragma unroll
    for (int kg = 0; kg < 8; ++kg) {
        const size_t pbase = (size_t)(b * 8 + kg) * L_ + q;
        const float4 pv = *(const float4*)&PW[pbase * D_ + c4 * 4];
        s[0] += pv.x; s[1] += pv.y; s[2] += pv.z; s[3] += pv.w;
        l += LW[pbase];
    }
    const float inv = 1.0f / l;
    float4 o;
    o.x = s[0] * inv; o.y = s[1] * inv; o.z = s[2] * inv; o.w = s[3] * inv;
    *(float4*)&O[((size_t)b * L_ + q) * D_ + c4 * 4] = o;
}

// ------------------------------------------------- fallback (R3, no ws) ----
#define NT 256
#define KS 72
__global__ __launch_bounds__(NT) void attn_mfma_f16(
    const float* __restrict__ Q, const float* __restrict__ K,
    const float* __restrict__ V, float* __restrict__ O)
{
    __shared__ __align__(16) _Float16 Kt[64 * KS];
    __shared__ __align__(16) _Float16 Vt[D_ * KS];
    __shared__ __align__(16) _Float16 Pt[4][16 * KS];

    const int t = threadIdx.x;
    const int wave = t >> 6, lane = t & 63, quad = lane >> 4, l15 = lane & 15;
    const int bpb = L_ / 64;
    const int b = blockIdx.x / bpb;
    const int qb = (blockIdx.x % bpb) * 64 + wave * 16;
    const size_t boff = (size_t)b * L_ * D_;

    half8_t aq[2];
    {
        const float* qp = Q + boff + (size_t)(qb + l15) * D_ + quad * 8;
        #pragma unroll
        for (int c = 0; c < 2; ++c) {
            const float4* p4 = (const float4*)(qp + c * 32);
            const float4 f0 = p4[0], f1 = p4[1];
            aq[c][0] = (_Float16)f0.x; aq[c][1] = (_Float16)f0.y;
            aq[c][2] = (_Float16)f0.z; aq[c][3] = (_Float16)f0.w;
            aq[c][4] = (_Float16)f1.x; aq[c][5] = (_Float16)f1.y;
            aq[c][6] = (_Float16)f1.z; aq[c][7] = (_Float16)f1.w;
        }
    }
    f32x4 ofr[4];
    #pragma unroll
    for (int d = 0; d < 4; ++d) ofr[d] = (f32x4){0.f, 0.f, 0.f, 0.f};
    float lacc[4] = {0.f, 0.f, 0.f, 0.f};
    const int skey = t & 63, sdg = t >> 6;
    _Float16* Pw = &Pt[wave][0];

    for (int kt = 0; kt < L_ / 64; ++kt) {
        __syncthreads();
        {
            const float4* kg4 = (const float4*)(K + boff + (size_t)(kt * 64 + skey) * D_ + sdg * 16);
            const float4 f0 = kg4[0], f1 = kg4[1], f2 = kg4[2], f3 = kg4[3];
            half8_t w0, w1;
            w0[0] = (_Float16)f0.x; w0[1] = (_Float16)f0.y;
            w0[2] = (_Float16)f0.z; w0[3] = (_Float16)f0.w;
            w0[4] = (_Float16)f1.x; w0[5] = (_Float16)f1.y;
            w0[6] = (_Float16)f1.z; w0[7] = (_Float16)f1.w;
            w1[0] = (_Float16)f2.x; w1[1] = (_Float16)f2.y;
            w1[2] = (_Float16)f2.z; w1[3] = (_Float16)f2.w;
            w1[4] = (_Float16)f3.x; w1[5] = (_Float16)f3.y;
            w1[6] = (_Float16)f3.z; w1[7] = (_Float16)f3.w;
            *(half8_t*)&Kt[skey * KS + sdg * 16] = w0;
            *(half8_t*)&Kt[skey * KS + sdg * 16 + 8] = w1;
        }
        {
            const float4* vg4 = (const float4*)(V + boff + (size_t)(kt * 64 + skey) * D_ + sdg * 16);
            #pragma unroll
            for (int i = 0; i < 4; ++i) {
                const float4 f = vg4[i];
                const int d0 = sdg * 16 + i * 4;
                Vt[(d0 + 0) * KS + skey] = (_Float16)f.x;
                Vt[(d0 + 1) * KS + skey] = (_Float16)f.y;
                Vt[(d0 + 2) * KS + skey] = (_Float16)f.z;
                Vt[(d0 + 3) * KS + skey] = (_Float16)f.w;
            }
        }
        __syncthreads();
        #pragma unroll
        for (int s = 0; s < 4; ++s) {
            const half8_t bk0 = *(const half8_t*)&Kt[(s * 16 + l15) * KS + quad * 8];
            const half8_t bk1 = *(const half8_t*)&Kt[(s * 16 + l15) * KS + 32 + quad * 8];
            f32x4 sc = (f32x4){0.f, 0.f, 0.f, 0.f};
            sc = __builtin_amdgcn_mfma_f32_16x16x32_f16(aq[0], bk0, sc, 0, 0, 0);
            sc = __builtin_amdgcn_mfma_f32_16x16x32_f16(aq[1], bk1, sc, 0, 0, 0);
            #pragma unroll
            for (int r = 0; r < 4; ++r) {
                const float p = __expf(sc[r] * 0.125f);
                lacc[r] += p;
                Pw[(quad * 4 + r) * KS + s * 16 + l15] = (_Float16)p;
            }
        }
        __syncthreads();
        #pragma unroll
        for (int c = 0; c < 2; ++c) {
            const half8_t ap = *(const half8_t*)&Pw[l15 * KS + c * 32 + quad * 8];
            #pragma unroll
            for (int d = 0; d < 4; ++d) {
                const half8_t bv = *(const half8_t*)&Vt[(d * 16 + l15) * KS + c * 32 + quad * 8];
                ofr[d] = __builtin_amdgcn_mfma_f32_16x16x32_f16(ap, bv, ofr[d], 0, 0, 0);
            }
        }
    }
    #pragma unroll
    for (int r = 0; r < 4; ++r) {
        float v = lacc[r];
        v += __shfl_xor(v, 1, 64);
        v += __shfl_xor(v, 2, 64);
        v += __shfl_xor(v, 4, 64);
        v += __shfl_xor(v, 8, 64);
        lacc[r] = v;
    }
    #pragma unroll
    for (int r = 0; r < 4; ++r) {
        const float inv = 1.0f / lacc[r];
        float* orow = O + boff + (size_t)(qb + quad * 4 + r) * D_ + l15;
        #pragma unroll
        for (int d = 0; d < 4; ++d) orow[d * 16] = ofr[d][r] * inv;
    }
}

extern "C" void kernel_launch(void* const* d_in, const int* in_sizes, int n_in,
                              void* d_out, int out_size, void* d_ws, size_t ws_size,
                              hipStream_t stream) {
    const float* Q = (const float*)d_in[0];
    const float* K = (const float*)d_in[1];
    const float* V = (const float*)d_in[2];
    float* O = (float*)d_out;

    // PW: [b(8)][kg(8)][q(2048)][64] fp32 = 32 MB ; LW: [b][kg][q] = 512 KB
    const size_t pw_elts = (size_t)B_ * 8 * L_ * D_;
    const size_t need = pw_elts * 4 + (size_t)B_ * 8 * L_ * 4;
    if (ws_size >= need) {
        float* PW = (float*)d_ws;
        float* LW = PW + pw_elts;
        attn_splitk<<<512, 512, 0, stream>>>(Q, K, V, PW, LW);
        combine<<<1024, 256, 0, stream>>>(PW, LW, O);
    } else {
        attn_mfma_f16<<<256, NT, 0, stream>>>(Q, K, V, O);
    }
}

// Round 3
// 95.757 us; speedup vs baseline: 1.0645x; 1.0645x over previous
//
#include <hip/hip_runtime.h>

// ScaledDotProductAttention B=8, L=2048, D=64, fp32 in/out.
//
// R16: single fused kernel, NO workspace (R2 post-mortem: dirtying 32 MB of ws
// slowed the timed 256 MiB re-poison fill 41->58 us; dur_us ~= fill + kernels,
// so ws must stay clean). Fixes R1's latency exposure by re-proportioning:
//   grid 256 = b(8) x qc(32: 64 queries), 1024 threads = 16 waves
//   = kg(8 key ranges of 256) x qg(2 query halves of 32). 4 waves/SIMD.
//   LDS 128 KB = 2 bufs x 8 tile-slots x (K 2048 | V 2048 halfs); per iter the
//   block stages one 32-key tile per kg slot (6 jobs/thread), so the whole
//   loop is 8 iterations / 8 barriers (R1 had 32). Pipeline order is R1's
//   proven { SWRITE(i+1); GLOAD(i+2); consume(i); barrier } - staged loads
//   get a full iteration to land; 4 waves/SIMD cover the rest.
// Per-CU traffic: LDS reads 1 MB (each tile visit serves 2 q-frags), global
// 1 MB fp32 K/V per block, L2-hot per XCD (b = blockIdx&7). Numerics are the
// verified R15 consume (swapped QK^T -> exp2 -> packed half4 PV via
// mfma_16x16x16f16, ks-paired V frags) and R0's verified LDS (O,l) combine,
// now 2 qg groups x 8 kg sources. absmax expectation unchanged.

#define B_ 8
#define L_ 2048
#define D_ 64

typedef _Float16 half8_t __attribute__((ext_vector_type(8)));
typedef _Float16 half4_t __attribute__((ext_vector_type(4)));
typedef float f32x4 __attribute__((ext_vector_type(4)));

#define SCALE_LOG2E 0.1803368801111244f   // 0.125 * log2(e)

__global__ __launch_bounds__(1024) void attn_fused2(
    const float* __restrict__ Q, const float* __restrict__ K,
    const float* __restrict__ V, float* __restrict__ O)
{
    // 2 bufs x 8 slots x 4096 halfs = 65536 halfs = 128 KB.
    __shared__ __align__(16) _Float16 FR[65536];

    const int t    = threadIdx.x;
    const int wave = t >> 6;
    const int lane = t & 63;
    const int quad = lane >> 4;
    const int l15  = lane & 15;
    const int kg   = wave >> 1;            // key range: [kg*256, +256)
    const int qg   = wave & 1;             // query half: 32 queries

    const int b  = blockIdx.x & 7;         // batch <-> XCD affinity
    const int qc = blockIdx.x >> 3;        // 0..31
    const int q0 = qc * 64 + qg * 32;

    const size_t boff = (size_t)b * L_ * D_;

    // ---------------- staging job constants (R15 prepass math) -------------
    // K: 2048 jobs/iter (8 slots x 4 planes x 64 lanes) -> 2/thread.
    int ksrc[2], kdst[2];
    #pragma unroll
    for (int j = 0; j < 2; ++j) {
        const int gk = j * 1024 + t;
        const int kgs = gk >> 8, kj = gk & 255;
        const int p = kj >> 6, jl = kj & 63;
        const int jq = jl >> 4, jl15 = jl & 15;
        const int s = p >> 1, c = p & 1;
        ksrc[j] = (kgs * 256 + s * 16 + jl15) * D_ + c * 32 + jq * 8;
        kdst[j] = kgs * 4096 + p * 512 + jl * 8;
    }
    // V: 4096 jobs/iter (8 slots x 8 planes x 64 lanes) -> 4/thread.
    int vsrc[4], vdst[4];
    #pragma unroll
    for (int j = 0; j < 4; ++j) {
        const int gv = j * 1024 + t;
        const int kgs = gv >> 9, vj = gv & 511;
        const int p = vj >> 6, jl = vj & 63;
        const int jq = jl >> 4, jl15 = jl & 15;
        const int d = p >> 1, ks = p & 1;
        vsrc[j] = (kgs * 256 + ks * 16 + jq * 4) * D_ + d * 16 + jl15;
        vdst[j] = kgs * 4096 + 2048 + d * 512 + jl * 8 + ks * 4;
    }

    // ---------------- Q B-frags from fp32, pre-scaled ----------------------
    half8_t bq[2][2];
    #pragma unroll
    for (int qs = 0; qs < 2; ++qs) {
        const float* qp = Q + boff + (size_t)(q0 + qs * 16 + l15) * D_ + quad * 8;
        #pragma unroll
        for (int c = 0; c < 2; ++c) {
            const float4 f0 = *(const float4*)(qp + c * 32);
            const float4 f1 = *(const float4*)(qp + c * 32 + 4);
            bq[qs][c][0] = (_Float16)(f0.x * SCALE_LOG2E);
            bq[qs][c][1] = (_Float16)(f0.y * SCALE_LOG2E);
            bq[qs][c][2] = (_Float16)(f0.z * SCALE_LOG2E);
            bq[qs][c][3] = (_Float16)(f0.w * SCALE_LOG2E);
            bq[qs][c][4] = (_Float16)(f1.x * SCALE_LOG2E);
            bq[qs][c][5] = (_Float16)(f1.y * SCALE_LOG2E);
            bq[qs][c][6] = (_Float16)(f1.z * SCALE_LOG2E);
            bq[qs][c][7] = (_Float16)(f1.w * SCALE_LOG2E);
        }
    }

    f32x4 ofr[2][4];
    #pragma unroll
    for (int qs = 0; qs < 2; ++qs)
        #pragma unroll
        for (int d = 0; d < 4; ++d)
            ofr[qs][d] = (f32x4){0.f, 0.f, 0.f, 0.f};
    float lacc[2] = {0.f, 0.f};

    // staged registers: one job set in flight (32 VGPR)
    float4 kf[2][2];
    float  vf[4][4];

#define GLOAD(TT)                                                              \
    {                                                                          \
        _Pragma("unroll") for (int j = 0; j < 2; ++j) {                        \
            const float* kp = K + boff + (size_t)(TT) * 32 * D_ + ksrc[j];     \
            kf[j][0] = *(const float4*)kp;                                     \
            kf[j][1] = *(const float4*)(kp + 4);                               \
        }                                                                      \
        _Pragma("unroll") for (int j = 0; j < 4; ++j) {                        \
            const float* vp = V + boff + (size_t)(TT) * 32 * D_ + vsrc[j];     \
            vf[j][0] = vp[0];      vf[j][1] = vp[D_];                          \
            vf[j][2] = vp[2 * D_]; vf[j][3] = vp[3 * D_];                      \
        }                                                                      \
    }

#define SWRITE(BUF)                                                            \
    {                                                                          \
        _Pragma("unroll") for (int j = 0; j < 2; ++j) {                        \
            half8_t w;                                                         \
            w[0] = (_Float16)kf[j][0].x; w[1] = (_Float16)kf[j][0].y;          \
            w[2] = (_Float16)kf[j][0].z; w[3] = (_Float16)kf[j][0].w;          \
            w[4] = (_Float16)kf[j][1].x; w[5] = (_Float16)kf[j][1].y;          \
            w[6] = (_Float16)kf[j][1].z; w[7] = (_Float16)kf[j][1].w;          \
            *(half8_t*)&FR[(BUF) * 32768 + kdst[j]] = w;                       \
        }                                                                      \
        _Pragma("unroll") for (int j = 0; j < 4; ++j) {                        \
            half4_t a;                                                         \
            a[0] = (_Float16)vf[j][0]; a[1] = (_Float16)vf[j][1];              \
            a[2] = (_Float16)vf[j][2]; a[3] = (_Float16)vf[j][3];              \
            *(half4_t*)&FR[(BUF) * 32768 + vdst[j]] = a;                       \
        }                                                                      \
    }

    // prologue: stage iter 0 into buf0, issue loads for iter 1
    GLOAD(0);
    SWRITE(0);
    GLOAD(1);
    __syncthreads();

    // ---- hot loop: 8 iterations, dbuf, one barrier each -------------------
    for (int i = 0; i < 8; ++i) {
        const int cb = (i & 1) * 32768;
        if (i < 7) {
            SWRITE((i & 1) ^ 1);              // iter i+1 -> other buf
            if (i < 6) GLOAD(i + 2);          // issue iter i+2 early
        }
        // consume slot kg of buf (tile = kg*8 + i), R15 PROC verbatim
        const _Float16* Kt = &FR[cb + kg * 4096];
        const _Float16* Vt = Kt + 2048;
        half8_t bk[2][2];
        #pragma unroll
        for (int s = 0; s < 2; ++s)
            #pragma unroll
            for (int c = 0; c < 2; ++c)
                bk[s][c] = *(const half8_t*)&Kt[(s * 2 + c) * 512 + lane * 8];
        half4_t pb[2][2];
        #pragma unroll
        for (int ks = 0; ks < 2; ++ks)
            #pragma unroll
            for (int qs = 0; qs < 2; ++qs) {
                f32x4 acc = (f32x4){0.f, 0.f, 0.f, 0.f};
                acc = __builtin_amdgcn_mfma_f32_16x16x32_f16(bk[ks][0], bq[qs][0], acc, 0, 0, 0);
                acc = __builtin_amdgcn_mfma_f32_16x16x32_f16(bk[ks][1], bq[qs][1], acc, 0, 0, 0);
                const float p0 = __builtin_exp2f(acc[0]);
                const float p1 = __builtin_exp2f(acc[1]);
                const float p2 = __builtin_exp2f(acc[2]);
                const float p3 = __builtin_exp2f(acc[3]);
                lacc[qs] += (p0 + p1) + (p2 + p3);
                half4_t pw;
                pw[0] = (_Float16)p0; pw[1] = (_Float16)p1;
                pw[2] = (_Float16)p2; pw[3] = (_Float16)p3;
                pb[ks][qs] = pw;
            }
        #pragma unroll
        for (int d = 0; d < 4; ++d) {
            const half8_t av8 = *(const half8_t*)&Vt[d * 512 + lane * 8];
            const half4_t alo = __builtin_shufflevector(av8, av8, 0, 1, 2, 3);
            const half4_t ahi = __builtin_shufflevector(av8, av8, 4, 5, 6, 7);
            #pragma unroll
            for (int qs = 0; qs < 2; ++qs) {
                ofr[qs][d] = __builtin_amdgcn_mfma_f32_16x16x16f16(alo, pb[0][qs], ofr[qs][d], 0, 0, 0);
                ofr[qs][d] = __builtin_amdgcn_mfma_f32_16x16x16f16(ahi, pb[1][qs], ofr[qs][d], 0, 0, 0);
            }
        }
        __syncthreads();
    }

    // ---- l: reduce over quads (lane holds partial for query qs*16+l15) ----
    float lsum[2];
    #pragma unroll
    for (int qs = 0; qs < 2; ++qs) {
        float v = lacc[qs];
        v += __shfl_xor(v, 16, 64);
        v += __shfl_xor(v, 32, 64);
        lsum[qs] = v;
    }

    // ---- cross-wave combine: 8 kg sources per qg group (R0 epilogue) ------
    float* RedO = (float*)&FR[0];               // [16 waves][64 lanes][17]
    float* RedL = RedO + 17408;                 // [16 waves][32]
    if (quad == 0) {
        RedL[wave * 32 + l15]      = lsum[0];
        RedL[wave * 32 + 16 + l15] = lsum[1];
    }

    #pragma unroll
    for (int qs = 0; qs < 2; ++qs) {
        __syncthreads();   // previous round's reads (and RedL writes) done
        float* dst = RedO + (wave * 64 + lane) * 17;
        #pragma unroll
        for (int d = 0; d < 4; ++d)
            #pragma unroll
            for (int r = 0; r < 4; ++r)
                dst[d * 4 + r] = ofr[qs][d][r];
        __syncthreads();
        if (wave < 8) {
            const int rkg = wave >> 1;          // output dim block 0..3
            const int rqg = wave & 1;           // query group to reduce
            float lt = 0.f;
            #pragma unroll
            for (int k2 = 0; k2 < 8; ++k2)
                lt += RedL[(k2 * 2 + rqg) * 32 + qs * 16 + l15];
            const float inv = 1.0f / lt;
            f32x4 osum = (f32x4){0.f, 0.f, 0.f, 0.f};
            #pragma unroll
            for (int k2 = 0; k2 < 8; ++k2) {
                const float* src = RedO + ((k2 * 2 + rqg) * 64 + lane) * 17 + rkg * 4;
                osum[0] += src[0]; osum[1] += src[1];
                osum[2] += src[2]; osum[3] += src[3];
            }
            float4 outv;
            outv.x = osum[0] * inv; outv.y = osum[1] * inv;
            outv.z = osum[2] * inv; outv.w = osum[3] * inv;
            // query = qc*64 + rqg*32 + qs*16 + l15 ; dims = rkg*16 + quad*4 ..
            *(float4*)&O[boff + (size_t)(qc * 64 + rqg * 32 + qs * 16 + l15) * D_
                         + rkg * 16 + quad * 4] = outv;
        }
    }
}

extern "C" void kernel_launch(void* const* d_in, const int* in_sizes, int n_in,
                              void* d_out, int out_size, void* d_ws, size_t ws_size,
                              hipStream_t stream) {
    const float* Q = (const float*)d_in[0];
    const float* K = (const float*)d_in[1];
    const float* V = (const float*)d_in[2];
    float* O = (float*)d_out;
    (void)d_ws; (void)ws_size;
    attn_fused2<<<256, 1024, 0, stream>>>(Q, K, V, O);
}

// Round 4
// 87.271 us; speedup vs baseline: 1.1681x; 1.0972x over previous
//
#include <hip/hip_runtime.h>

// ScaledDotProductAttention B=8, L=2048, D=64, fp32 in/out.
//
// R17 = R0's verified two-phase structure with Q-tile 64 (was 32).
// Post-mortem R1/R3: fused single-kernel variants are stuck at ~51 us
// regardless of occupancy/barriers -> bound by their fp32 byte stream +
// scalar V gathers + LDS round-trip, not latency. R0's frag-stream attn
// (28 us) wins structurally; its cost scales with (blocks/batch) x frag
// bytes, so doubling the per-block query tile halves tile-visits
// (32768 -> 16384) and the fragment stream (256 -> 128 MB).
//  1) prepass_frag: K/V -> f16 MFMA fragments in ws, R0 math verbatim,
//     but block->batch mapping is now XCD-ALIGNED (b = blk&7) so batch-b
//     frags are written by XCD b and re-read by XCD b (attn uses
//     b = blockIdx&7): frag reads become same-L2 hits (were 7/8 cross-XCD).
//  2) attn_q64: 256 blocks = b(8) x qblock(32 of 64 queries); 512 thr =
//     8 waves = kg owners (256 keys = 8 tiles each). Per wave: 4 q-frags.
//     Zero LDS / zero cross-lane hot loop (R9/R13-verified algebra):
//       - S^T = K*Q^T via mfma_f32_16x16x32_f16 (0.125*log2e folded into Q);
//       - p = exp2(s); packed half4 IS the B-frag of mfma_f32_16x16x16f16;
//       - PV: O^T += VT16F half4 A-frags x P^T.
//     K AND V frags double-buffered (V prefetch is new: covers L2 latency
//     at 2 waves/SIMD; VGPR ~210 <= 256). Epilogue: 4 rounds over 36 KB
//     LDS; 8-wave (O,l) combine (R0 pattern, qs->qf rounds).
// Fallback: proven fused kernel path if ws too small.

#define B_ 8
#define L_ 2048
#define D_ 64
#define NT 256

typedef _Float16 half8_t __attribute__((ext_vector_type(8)));
typedef _Float16 half4_t __attribute__((ext_vector_type(4)));
typedef float f32x4 __attribute__((ext_vector_type(4)));

#define SCALE_LOG2E 0.1803368801111244f   // 0.125 * log2(e)

// ------------------------------------------------------------ prepass_frag --
// blocks 0..511: K fragments; 512..1023: V^T fragments. XCD-aligned batches.
__global__ __launch_bounds__(NT) void prepass_frag(
    const float* __restrict__ K, const float* __restrict__ V,
    _Float16* __restrict__ K16F, _Float16* __restrict__ VT16F)
{
    const int blk = blockIdx.x;
    const int t = threadIdx.x;
    if (blk < 512) {
        const int b  = blk & 7;           // XCD-aligned (blk%8 -> XCD)
        const int kt = blk >> 3;          // 0..63
        const int p    = t >> 6;          // plane = s*2 + c
        const int lane = t & 63;
        const int quad = lane >> 4;
        const int l15  = lane & 15;
        const int s = p >> 1, c = p & 1;
        const int row = kt * 32 + s * 16 + l15;
        const float* kp = K + ((size_t)b * L_ + row) * D_ + c * 32 + quad * 8;
        const float4 f0 = *(const float4*)kp;
        const float4 f1 = *(const float4*)(kp + 4);
        half8_t w;
        w[0] = (_Float16)f0.x; w[1] = (_Float16)f0.y;
        w[2] = (_Float16)f0.z; w[3] = (_Float16)f0.w;
        w[4] = (_Float16)f1.x; w[5] = (_Float16)f1.y;
        w[6] = (_Float16)f1.z; w[7] = (_Float16)f1.w;
        *(half8_t*)&K16F[((size_t)(b * 64 + kt) * 4 + p) * 512 + lane * 8] = w;
    } else {
        const int vb = blk - 512;
        const int b  = vb & 7;            // XCD-aligned
        const int kt = vb >> 3;
        #pragma unroll
        for (int i = 0; i < 2; ++i) {
            const int slot = i * NT + t;      // 512 slots = 8 planes x 64 lanes
            const int p    = slot >> 6;       // plane = d*2 + ks
            const int lane = slot & 63;
            const int quad = lane >> 4;
            const int l15  = lane & 15;
            const int d = p >> 1, ks = p & 1;
            const int row = kt * 32 + ks * 16 + quad * 4;
            const int col = d * 16 + l15;
            const float* vp = V + ((size_t)b * L_ + row) * D_ + col;
            half4_t a;
            a[0] = (_Float16)vp[0];
            a[1] = (_Float16)vp[D_];
            a[2] = (_Float16)vp[2 * D_];
            a[3] = (_Float16)vp[3 * D_];
            *(half4_t*)&VT16F[((size_t)(b * 64 + kt) * 8 + p) * 256 + lane * 4] = a;
        }
    }
}

// -------------------------------------------------------------- attn_q64 ---

#define LOADK(KT, BK)                                                           \
    {                                                                           \
        const int ktc_ = (KT) & 63;                                             \
        _Pragma("unroll") for (int s = 0; s < 2; ++s)                           \
        _Pragma("unroll") for (int c = 0; c < 2; ++c)                           \
            BK[s][c] = *(const half8_t*)&KbF[((size_t)ktc_ * 4 + s * 2 + c) * 512 + lane * 8]; \
    }

#define LOADV(KT, AV)                                                           \
    {                                                                           \
        const int ktc_ = (KT) & 63;                                             \
        _Pragma("unroll") for (int d = 0; d < 4; ++d)                           \
        _Pragma("unroll") for (int ks = 0; ks < 2; ++ks)                        \
            AV[d][ks] = *(const half4_t*)&VbF[((size_t)ktc_ * 8 + d * 2 + ks) * 256 + lane * 4]; \
    }

#define PROC(BK, AV)                                                            \
    {                                                                           \
        half4_t pb[2][4];                                                       \
        _Pragma("unroll") for (int ks = 0; ks < 2; ++ks)                        \
        _Pragma("unroll") for (int qf = 0; qf < 4; ++qf) {                      \
            f32x4 acc = (f32x4){0.f, 0.f, 0.f, 0.f};                            \
            acc = __builtin_amdgcn_mfma_f32_16x16x32_f16(BK[ks][0], bq[qf][0], acc, 0, 0, 0); \
            acc = __builtin_amdgcn_mfma_f32_16x16x32_f16(BK[ks][1], bq[qf][1], acc, 0, 0, 0); \
            const float p0 = __builtin_exp2f(acc[0]);                           \
            const float p1 = __builtin_exp2f(acc[1]);                           \
            const float p2 = __builtin_exp2f(acc[2]);                           \
            const float p3 = __builtin_exp2f(acc[3]);                           \
            lacc[qf] += (p0 + p1) + (p2 + p3);                                  \
            half4_t pv;                                                         \
            pv[0] = (_Float16)p0; pv[1] = (_Float16)p1;                         \
            pv[2] = (_Float16)p2; pv[3] = (_Float16)p3;                         \
            pb[ks][qf] = pv;                                                    \
        }                                                                       \
        _Pragma("unroll") for (int qf = 0; qf < 4; ++qf)                        \
        _Pragma("unroll") for (int d = 0; d < 4; ++d)                           \
        _Pragma("unroll") for (int ks = 0; ks < 2; ++ks)                        \
            ofr[qf][d] = __builtin_amdgcn_mfma_f32_16x16x16f16(AV[d][ks], pb[ks][qf], ofr[qf][d], 0, 0, 0); \
    }

__global__ __launch_bounds__(512, 2) void attn_q64(
    const float* __restrict__ Q,
    const _Float16* __restrict__ K16F,
    const _Float16* __restrict__ VT16F,
    float* __restrict__ O)
{
    __shared__ float Ored[512 * 17];                     // 34816 B (epilogue)
    __shared__ float Lred[512];                          // 2 KB

    const int t    = threadIdx.x;
    const int wave = t >> 6;                   // 0..7 (key-range owner)
    const int lane = t & 63;
    const int quad = lane >> 4;
    const int l15  = lane & 15;

    const int b   = blockIdx.x & 7;            // batch <-> XCD affinity
    const int qbi = blockIdx.x >> 3;           // query block 0..31
    const int qb  = qbi * 64;
    const int kt0 = wave * 8;                  // wave's 8 tiles (256 keys)

    const _Float16* KbF = K16F + (size_t)b * 64 * 4 * 512;
    const _Float16* VbF = VT16F + (size_t)b * 64 * 8 * 256;

    // ---- Q B-frags from fp32, pre-scaled by 0.125*log2(e): 4 q-frags ----
    half8_t bq[4][2];
    #pragma unroll
    for (int qf = 0; qf < 4; ++qf) {
        const float* qp = Q + ((size_t)b * L_ + qb + qf * 16 + l15) * D_ + quad * 8;
        #pragma unroll
        for (int c = 0; c < 2; ++c) {
            const float4 f0 = *(const float4*)(qp + c * 32);
            const float4 f1 = *(const float4*)(qp + c * 32 + 4);
            bq[qf][c][0] = (_Float16)(f0.x * SCALE_LOG2E);
            bq[qf][c][1] = (_Float16)(f0.y * SCALE_LOG2E);
            bq[qf][c][2] = (_Float16)(f0.z * SCALE_LOG2E);
            bq[qf][c][3] = (_Float16)(f0.w * SCALE_LOG2E);
            bq[qf][c][4] = (_Float16)(f1.x * SCALE_LOG2E);
            bq[qf][c][5] = (_Float16)(f1.y * SCALE_LOG2E);
            bq[qf][c][6] = (_Float16)(f1.z * SCALE_LOG2E);
            bq[qf][c][7] = (_Float16)(f1.w * SCALE_LOG2E);
        }
    }

    f32x4 ofr[4][4];
    #pragma unroll
    for (int qf = 0; qf < 4; ++qf)
        #pragma unroll
        for (int d = 0; d < 4; ++d)
            ofr[qf][d] = (f32x4){0.f, 0.f, 0.f, 0.f};
    float lacc[4] = {0.f, 0.f, 0.f, 0.f};

    // ---- hot loop: 8 tiles of 32 keys; K and V frags double-buffered ----
    half8_t bkA[2][2], bkB[2][2];
    half4_t avA[4][2], avB[4][2];
    LOADK(kt0, bkA);
    LOADV(kt0, avA);
    for (int it = 0; it < 4; ++it) {
        const int kta = kt0 + it * 2;
        LOADK(kta + 1, bkB);
        LOADV(kta + 1, avB);
        PROC(bkA, avA);
        LOADK(kta + 2, bkA);      // tile index clamped (&63) inside macro
        LOADV(kta + 2, avA);
        PROC(bkB, avB);
    }

    // ---- l: reduce over quads (each lane holds 4 keys of query qf*16+l15) --
    #pragma unroll
    for (int qf = 0; qf < 4; ++qf) {
        float v = lacc[qf];
        v += __shfl_xor(v, 16, 64);
        v += __shfl_xor(v, 32, 64);
        lacc[qf] = v;
    }
    if (quad == 0) {
        #pragma unroll
        for (int qf = 0; qf < 4; ++qf)
            Lred[wave * 64 + qf * 16 + l15] = lacc[qf];
    }

    // ---- cross-wave combine: 4 rounds (one q-frag each) -------------------
    #pragma unroll
    for (int qf = 0; qf < 4; ++qf) {
        __syncthreads();   // previous round's reads (and Lred writes) done
        float* dst = &Ored[(wave * 64 + lane) * 17];
        #pragma unroll
        for (int d = 0; d < 4; ++d)
            #pragma unroll
            for (int r = 0; r < 4; ++r)
                dst[d * 4 + r] = ofr[qf][d][r];
        __syncthreads();
        if (wave < 4) {
            float lt = 0.f;
            #pragma unroll
            for (int w2 = 0; w2 < 8; ++w2)
                lt += Lred[w2 * 64 + qf * 16 + l15];
            const float inv = 1.0f / lt;
            f32x4 osum = (f32x4){0.f, 0.f, 0.f, 0.f};
            #pragma unroll
            for (int w2 = 0; w2 < 8; ++w2) {
                const float* src = &Ored[(w2 * 64 + lane) * 17 + wave * 4];
                osum[0] += src[0]; osum[1] += src[1];
                osum[2] += src[2]; osum[3] += src[3];
            }
            float4 outv;
            outv.x = osum[0] * inv; outv.y = osum[1] * inv;
            outv.z = osum[2] * inv; outv.w = osum[3] * inv;
            // query = qb + qf*16 + l15 ; dims = wave*16 + quad*4 .. +4
            *(float4*)&O[((size_t)b * L_ + qb + qf * 16 + l15) * D_ + wave * 16 + quad * 4] = outv;
        }
    }
}

// ------------------------------------------------- fallback (R3, no ws) ----
#define KS 72
__global__ __launch_bounds__(NT) void attn_mfma_f16(
    const float* __restrict__ Q, const float* __restrict__ K,
    const float* __restrict__ V, float* __restrict__ O)
{
    __shared__ __align__(16) _Float16 Kt[64 * KS];
    __shared__ __align__(16) _Float16 Vt[D_ * KS];
    __shared__ __align__(16) _Float16 Pt[4][16 * KS];

    const int t = threadIdx.x;
    const int wave = t >> 6, lane = t & 63, quad = lane >> 4, l15 = lane & 15;
    const int bpb = L_ / 64;
    const int b = blockIdx.x / bpb;
    const int qb = (blockIdx.x % bpb) * 64 + wave * 16;
    const size_t boff = (size_t)b * L_ * D_;

    half8_t aq[2];
    {
        const float* qp = Q + boff + (size_t)(qb + l15) * D_ + quad * 8;
        #pragma unroll
        for (int c = 0; c < 2; ++c) {
            const float4* p4 = (const float4*)(qp + c * 32);
            const float4 f0 = p4[0], f1 = p4[1];
            aq[c][0] = (_Float16)f0.x; aq[c][1] = (_Float16)f0.y;
            aq[c][2] = (_Float16)f0.z; aq[c][3] = (_Float16)f0.w;
            aq[c][4] = (_Float16)f1.x; aq[c][5] = (_Float16)f1.y;
            aq[c][6] = (_Float16)f1.z; aq[c][7] = (_Float16)f1.w;
        }
    }
    f32x4 ofr[4];
    #pragma unroll
    for (int d = 0; d < 4; ++d) ofr[d] = (f32x4){0.f, 0.f, 0.f, 0.f};
    float lacc[4] = {0.f, 0.f, 0.f, 0.f};
    const int skey = t & 63, sdg = t >> 6;
    _Float16* Pw = &Pt[wave][0];

    for (int kt = 0; kt < L_ / 64; ++kt) {
        __syncthreads();
        {
            const float4* kg4 = (const float4*)(K + boff + (size_t)(kt * 64 + skey) * D_ + sdg * 16);
            const float4 f0 = kg4[0], f1 = kg4[1], f2 = kg4[2], f3 = kg4[3];
            half8_t w0, w1;
            w0[0] = (_Float16)f0.x; w0[1] = (_Float16)f0.y;
            w0[2] = (_Float16)f0.z; w0[3] = (_Float16)f0.w;
            w0[4] = (_Float16)f1.x; w0[5] = (_Float16)f1.y;
            w0[6] = (_Float16)f1.z; w0[7] = (_Float16)f1.w;
            w1[0] = (_Float16)f2.x; w1[1] = (_Float16)f2.y;
            w1[2] = (_Float16)f2.z; w1[3] = (_Float16)f2.w;
            w1[4] = (_Float16)f3.x; w1[5] = (_Float16)f3.y;
            w1[6] = (_Float16)f3.z; w1[7] = (_Float16)f3.w;
            *(half8_t*)&Kt[skey * KS + sdg * 16] = w0;
            *(half8_t*)&Kt[skey * KS + sdg * 16 + 8] = w1;
        }
        {
            const float4* vg4 = (const float4*)(V + boff + (size_t)(kt * 64 + skey) * D_ + sdg * 16);
            #pragma unroll
            for (int i = 0; i < 4; ++i) {
                const float4 f = vg4[i];
                const int d0 = sdg * 16 + i * 4;
                Vt[(d0 + 0) * KS + skey] = (_Float16)f.x;
                Vt[(d0 + 1) * KS + skey] = (_Float16)f.y;
                Vt[(d0 + 2) * KS + skey] = (_Float16)f.z;
                Vt[(d0 + 3) * KS + skey] = (_Float16)f.w;
            }
        }
        __syncthreads();
        #pragma unroll
        for (int s = 0; s < 4; ++s) {
            const half8_t bk0 = *(const half8_t*)&Kt[(s * 16 + l15) * KS + quad * 8];
            const half8_t bk1 = *(const half8_t*)&Kt[(s * 16 + l15) * KS + 32 + quad * 8];
            f32x4 sc = (f32x4){0.f, 0.f, 0.f, 0.f};
            sc = __builtin_amdgcn_mfma_f32_16x16x32_f16(aq[0], bk0, sc, 0, 0, 0);
            sc = __builtin_amdgcn_mfma_f32_16x16x32_f16(aq[1], bk1, sc, 0, 0, 0);
            #pragma unroll
            for (int r = 0; r < 4; ++r) {
                const float p = __expf(sc[r] * 0.125f);
                lacc[r] += p;
                Pw[(quad * 4 + r) * KS + s * 16 + l15] = (_Float16)p;
            }
        }
        __syncthreads();
        #pragma unroll
        for (int c = 0; c < 2; ++c) {
            const half8_t ap = *(const half8_t*)&Pw[l15 * KS + c * 32 + quad * 8];
            #pragma unroll
            for (int d = 0; d < 4; ++d) {
                const half8_t bv = *(const half8_t*)&Vt[(d * 16 + l15) * KS + c * 32 + quad * 8];
                ofr[d] = __builtin_amdgcn_mfma_f32_16x16x32_f16(ap, bv, ofr[d], 0, 0, 0);
            }
        }
    }
    #pragma unroll
    for (int r = 0; r < 4; ++r) {
        float v = lacc[r];
        v += __shfl_xor(v, 1, 64);
        v += __shfl_xor(v, 2, 64);
        v += __shfl_xor(v, 4, 64);
        v += __shfl_xor(v, 8, 64);
        lacc[r] = v;
    }
    #pragma unroll
    for (int r = 0; r < 4; ++r) {
        const float inv = 1.0f / lacc[r];
        float* orow = O + boff + (size_t)(qb + quad * 4 + r) * D_ + l15;
        #pragma unroll
        for (int d = 0; d < 4; ++d) orow[d * 16] = ofr[d][r] * inv;
    }
}

extern "C" void kernel_launch(void* const* d_in, const int* in_sizes, int n_in,
                              void* d_out, int out_size, void* d_ws, size_t ws_size,
                              hipStream_t stream) {
    const float* Q = (const float*)d_in[0];
    const float* K = (const float*)d_in[1];
    const float* V = (const float*)d_in[2];
    float* O = (float*)d_out;

    if (ws_size >= (size_t)8 * 1024 * 1024) {
        _Float16* K16F  = (_Float16*)d_ws;                             // 2 MB
        _Float16* VT16F = K16F + (size_t)1048576;                      // 2 MB
        prepass_frag<<<1024, NT, 0, stream>>>(K, V, K16F, VT16F);
        attn_q64<<<256, 512, 0, stream>>>(Q, K16F, VT16F, O);
    } else {
        attn_mfma_f16<<<256, NT, 0, stream>>>(Q, K, V, O);
    }
}

// Round 5
// 83.982 us; speedup vs baseline: 1.2138x; 1.0392x over previous
//
#include <hip/hip_runtime.h>

// ScaledDotProductAttention B=8, L=2048, D=64, fp32 in/out.
//
// R18: two-phase frag structure; attn at q-tile 64 AND full TLP.
// Timing model fitted over R0-R4: dur ~= fill(~42) + kernels + ~11 us fixed.
//   R0 attn ~27 us (268 MB frag stream -> 9.9 TB/s eff: L3-resident),
//   R4 attn ~29 us (134 MB at 2 waves/SIMD -> 4.6 TB/s): achieved BW scales
//   with waves in flight => latency/TLP-bound on an L3-resident stream.
// Fix: 256 blocks x 1024 thr = 16 waves/CU (4/SIMD, R0's TLP) with
// wave = kg(8 key ranges of 256) x qg(2 query halves), 2 q-frags/wave
// (R0's VGPR footprint ~125 <= 128 cap from __launch_bounds__(1024)).
// Stream stays 128 MB (R4's q-tile-64 total) at R0's effective BW.
//  1) prepass_frag (XCD-aligned b=blk&7, matches attn's b=blockIdx&7):
//     K frags unchanged; V frags now ks-PAIRED (R15/R16-verified layout:
//     ((b*64+kt)*4+d)*512 + lane*8 + ks*4) so attn's LOADV is 4 x b128.
//  2) attn_q64w16: zero-LDS zero-barrier hot loop (R9/R13 algebra):
//       - S^T = K*Q^T via mfma_f32_16x16x32_f16 (0.125*log2e folded into Q);
//       - p = exp2(s); packed half4 IS the B-frag of mfma_f32_16x16x16f16;
//       - PV: O^T += V^T half4 A-frags x P^T (R16 consume verbatim).
//     K frags double-buffered one tile ahead; V single-set issued before
//     the QK/softmax phase (~400 cyc cover). Epilogue: R3's verified
//     16-wave (O,l) combine, 2 qs rounds, dedicated 71 KB LDS.
// Fallback: proven R3 kernel if ws too small.

#define B_ 8
#define L_ 2048
#define D_ 64
#define NT 256

typedef _Float16 half8_t __attribute__((ext_vector_type(8)));
typedef _Float16 half4_t __attribute__((ext_vector_type(4)));
typedef float f32x4 __attribute__((ext_vector_type(4)));

#define SCALE_LOG2E 0.1803368801111244f   // 0.125 * log2(e)

// ------------------------------------------------------------ prepass_frag --
// blocks 0..511: K fragments; 512..1023: V^T fragments. XCD-aligned batches.
__global__ __launch_bounds__(NT) void prepass_frag(
    const float* __restrict__ K, const float* __restrict__ V,
    _Float16* __restrict__ K16F, _Float16* __restrict__ VT16F)
{
    const int blk = blockIdx.x;
    const int t = threadIdx.x;
    if (blk < 512) {
        const int b  = blk & 7;           // XCD-aligned (blk%8 -> XCD)
        const int kt = blk >> 3;          // 0..63
        const int p    = t >> 6;          // plane = s*2 + c
        const int lane = t & 63;
        const int quad = lane >> 4;
        const int l15  = lane & 15;
        const int s = p >> 1, c = p & 1;
        const int row = kt * 32 + s * 16 + l15;
        const float* kp = K + ((size_t)b * L_ + row) * D_ + c * 32 + quad * 8;
        const float4 f0 = *(const float4*)kp;
        const float4 f1 = *(const float4*)(kp + 4);
        half8_t w;
        w[0] = (_Float16)f0.x; w[1] = (_Float16)f0.y;
        w[2] = (_Float16)f0.z; w[3] = (_Float16)f0.w;
        w[4] = (_Float16)f1.x; w[5] = (_Float16)f1.y;
        w[6] = (_Float16)f1.z; w[7] = (_Float16)f1.w;
        *(half8_t*)&K16F[((size_t)(b * 64 + kt) * 4 + p) * 512 + lane * 8] = w;
    } else {
        const int vb = blk - 512;
        const int b  = vb & 7;            // XCD-aligned
        const int kt = vb >> 3;
        #pragma unroll
        for (int i = 0; i < 2; ++i) {
            const int slot = i * NT + t;      // 512 slots = 8 planes x 64 lanes
            const int p    = slot >> 6;       // plane = d*2 + ks
            const int lane = slot & 63;
            const int quad = lane >> 4;
            const int l15  = lane & 15;
            const int d = p >> 1, ks = p & 1;
            const int row = kt * 32 + ks * 16 + quad * 4;
            const int col = d * 16 + l15;
            const float* vp = V + ((size_t)b * L_ + row) * D_ + col;
            half4_t a;
            a[0] = (_Float16)vp[0];
            a[1] = (_Float16)vp[D_];
            a[2] = (_Float16)vp[2 * D_];
            a[3] = (_Float16)vp[3 * D_];
            // ks-paired layout (R15/R16-verified): one b128 per (tile,d)
            *(half4_t*)&VT16F[((size_t)(b * 64 + kt) * 4 + d) * 512 + lane * 8 + ks * 4] = a;
        }
    }
}

// ------------------------------------------------------------ attn_q64w16 --

#define LOADK(KT, BK)                                                           \
    {                                                                           \
        const int ktc_ = (KT) & 63;                                             \
        _Pragma("unroll") for (int s = 0; s < 2; ++s)                           \
        _Pragma("unroll") for (int c = 0; c < 2; ++c)                           \
            BK[s][c] = *(const half8_t*)&KbF[((size_t)ktc_ * 4 + s * 2 + c) * 512 + lane * 8]; \
    }

#define LOADV(KT, AV)                                                           \
    {                                                                           \
        const int ktc_ = (KT) & 63;                                             \
        _Pragma("unroll") for (int d = 0; d < 4; ++d)                           \
            AV[d] = *(const half8_t*)&VbF[((size_t)ktc_ * 4 + d) * 512 + lane * 8]; \
    }

#define PROC(BK, AV)                                                            \
    {                                                                           \
        half4_t pb[2][2];                                                       \
        _Pragma("unroll") for (int ks = 0; ks < 2; ++ks)                        \
        _Pragma("unroll") for (int qs = 0; qs < 2; ++qs) {                      \
            f32x4 acc = (f32x4){0.f, 0.f, 0.f, 0.f};                            \
            acc = __builtin_amdgcn_mfma_f32_16x16x32_f16(BK[ks][0], bq[qs][0], acc, 0, 0, 0); \
            acc = __builtin_amdgcn_mfma_f32_16x16x32_f16(BK[ks][1], bq[qs][1], acc, 0, 0, 0); \
            const float p0 = __builtin_exp2f(acc[0]);                           \
            const float p1 = __builtin_exp2f(acc[1]);                           \
            const float p2 = __builtin_exp2f(acc[2]);                           \
            const float p3 = __builtin_exp2f(acc[3]);                           \
            lacc[qs] += (p0 + p1) + (p2 + p3);                                  \
            half4_t pv;                                                         \
            pv[0] = (_Float16)p0; pv[1] = (_Float16)p1;                         \
            pv[2] = (_Float16)p2; pv[3] = (_Float16)p3;                         \
            pb[ks][qs] = pv;                                                    \
        }                                                                       \
        _Pragma("unroll") for (int d = 0; d < 4; ++d) {                         \
            const half4_t alo = __builtin_shufflevector(AV[d], AV[d], 0, 1, 2, 3); \
            const half4_t ahi = __builtin_shufflevector(AV[d], AV[d], 4, 5, 6, 7); \
            _Pragma("unroll") for (int qs = 0; qs < 2; ++qs) {                  \
                ofr[qs][d] = __builtin_amdgcn_mfma_f32_16x16x16f16(alo, pb[0][qs], ofr[qs][d], 0, 0, 0); \
                ofr[qs][d] = __builtin_amdgcn_mfma_f32_16x16x16f16(ahi, pb[1][qs], ofr[qs][d], 0, 0, 0); \
            }                                                                   \
        }                                                                       \
    }

__global__ __launch_bounds__(1024) void attn_q64w16(
    const float* __restrict__ Q,
    const _Float16* __restrict__ K16F,
    const _Float16* __restrict__ VT16F,
    float* __restrict__ O)
{
    __shared__ float Ored[1024 * 17];                    // 69632 B (epilogue)
    __shared__ float Lred[512];                          // 2 KB

    const int t    = threadIdx.x;
    const int wave = t >> 6;                   // 0..15
    const int lane = t & 63;
    const int quad = lane >> 4;
    const int l15  = lane & 15;
    const int kg   = wave >> 1;                // key range [kg*256, +256)
    const int qg   = wave & 1;                 // query half (32 queries)

    const int b   = blockIdx.x & 7;            // batch <-> XCD affinity
    const int qbi = blockIdx.x >> 3;           // query block 0..31
    const int qb  = qbi * 64;
    const int q0  = qb + qg * 32;
    const int kt0 = kg * 8;                    // wave's 8 tiles (256 keys)

    const _Float16* KbF = K16F + (size_t)b * 64 * 4 * 512;
    const _Float16* VbF = VT16F + (size_t)b * 64 * 4 * 512;

    // ---- Q B-frags from fp32, pre-scaled by 0.125*log2(e) ----
    half8_t bq[2][2];
    #pragma unroll
    for (int qs = 0; qs < 2; ++qs) {
        const float* qp = Q + ((size_t)b * L_ + q0 + qs * 16 + l15) * D_ + quad * 8;
        #pragma unroll
        for (int c = 0; c < 2; ++c) {
            const float4 f0 = *(const float4*)(qp + c * 32);
            const float4 f1 = *(const float4*)(qp + c * 32 + 4);
            bq[qs][c][0] = (_Float16)(f0.x * SCALE_LOG2E);
            bq[qs][c][1] = (_Float16)(f0.y * SCALE_LOG2E);
            bq[qs][c][2] = (_Float16)(f0.z * SCALE_LOG2E);
            bq[qs][c][3] = (_Float16)(f0.w * SCALE_LOG2E);
            bq[qs][c][4] = (_Float16)(f1.x * SCALE_LOG2E);
            bq[qs][c][5] = (_Float16)(f1.y * SCALE_LOG2E);
            bq[qs][c][6] = (_Float16)(f1.z * SCALE_LOG2E);
            bq[qs][c][7] = (_Float16)(f1.w * SCALE_LOG2E);
        }
    }

    f32x4 ofr[2][4];
    #pragma unroll
    for (int qs = 0; qs < 2; ++qs)
        #pragma unroll
        for (int d = 0; d < 4; ++d)
            ofr[qs][d] = (f32x4){0.f, 0.f, 0.f, 0.f};
    float lacc[2] = {0.f, 0.f};

    // ---- hot loop: 8 tiles of 32 keys; K dbuf one tile ahead, V per-tile ---
    half8_t bkA[2][2], bkB[2][2], av[4];
    LOADK(kt0, bkA);
    for (int it = 0; it < 4; ++it) {
        const int kta = kt0 + it * 2;
        LOADK(kta + 1, bkB);
        LOADV(kta, av);           // covered by QK+softmax of PROC below
        PROC(bkA, av);
        LOADK(kta + 2, bkA);      // tile index clamped (&63) inside macro
        LOADV(kta + 1, av);
        PROC(bkB, av);
    }

    // ---- l: reduce over quads (lane holds partial for query qs*16+l15) ----
    float lsum[2];
    #pragma unroll
    for (int qs = 0; qs < 2; ++qs) {
        float v = lacc[qs];
        v += __shfl_xor(v, 16, 64);
        v += __shfl_xor(v, 32, 64);
        lsum[qs] = v;
    }
    if (quad == 0) {
        Lred[wave * 32 + l15]      = lsum[0];
        Lred[wave * 32 + 16 + l15] = lsum[1];
    }

    // ---- cross-wave combine: 8 kg sources per qg group (R3 verbatim) ------
    #pragma unroll
    for (int qs = 0; qs < 2; ++qs) {
        __syncthreads();   // previous round's reads (and Lred writes) done
        float* dst = &Ored[(wave * 64 + lane) * 17];
        #pragma unroll
        for (int d = 0; d < 4; ++d)
            #pragma unroll
            for (int r = 0; r < 4; ++r)
                dst[d * 4 + r] = ofr[qs][d][r];
        __syncthreads();
        if (wave < 8) {
            const int rkg = wave >> 1;          // output dim block 0..3
            const int rqg = wave & 1;           // query group to reduce
            float lt = 0.f;
            #pragma unroll
            for (int k2 = 0; k2 < 8; ++k2)
                lt += Lred[(k2 * 2 + rqg) * 32 + qs * 16 + l15];
            const float inv = 1.0f / lt;
            f32x4 osum = (f32x4){0.f, 0.f, 0.f, 0.f};
            #pragma unroll
            for (int k2 = 0; k2 < 8; ++k2) {
                const float* src = &Ored[((k2 * 2 + rqg) * 64 + lane) * 17 + rkg * 4];
                osum[0] += src[0]; osum[1] += src[1];
                osum[2] += src[2]; osum[3] += src[3];
            }
            float4 outv;
            outv.x = osum[0] * inv; outv.y = osum[1] * inv;
            outv.z = osum[2] * inv; outv.w = osum[3] * inv;
            // query = qb + rqg*32 + qs*16 + l15 ; dims = rkg*16 + quad*4 .. +4
            *(float4*)&O[((size_t)b * L_ + qb + rqg * 32 + qs * 16 + l15) * D_
                         + rkg * 16 + quad * 4] = outv;
        }
    }
}

// ------------------------------------------------- fallback (R3, no ws) ----
#define KS 72
__global__ __launch_bounds__(NT) void attn_mfma_f16(
    const float* __restrict__ Q, const float* __restrict__ K,
    const float* __restrict__ V, float* __restrict__ O)
{
    __shared__ __align__(16) _Float16 Kt[64 * KS];
    __shared__ __align__(16) _Float16 Vt[D_ * KS];
    __shared__ __align__(16) _Float16 Pt[4][16 * KS];

    const int t = threadIdx.x;
    const int wave = t >> 6, lane = t & 63, quad = lane >> 4, l15 = lane & 15;
    const int bpb = L_ / 64;
    const int b = blockIdx.x / bpb;
    const int qb = (blockIdx.x % bpb) * 64 + wave * 16;
    const size_t boff = (size_t)b * L_ * D_;

    half8_t aq[2];
    {
        const float* qp = Q + boff + (size_t)(qb + l15) * D_ + quad * 8;
        #pragma unroll
        for (int c = 0; c < 2; ++c) {
            const float4* p4 = (const float4*)(qp + c * 32);
            const float4 f0 = p4[0], f1 = p4[1];
            aq[c][0] = (_Float16)f0.x; aq[c][1] = (_Float16)f0.y;
            aq[c][2] = (_Float16)f0.z; aq[c][3] = (_Float16)f0.w;
            aq[c][4] = (_Float16)f1.x; aq[c][5] = (_Float16)f1.y;
            aq[c][6] = (_Float16)f1.z; aq[c][7] = (_Float16)f1.w;
        }
    }
    f32x4 ofr[4];
    #pragma unroll
    for (int d = 0; d < 4; ++d) ofr[d] = (f32x4){0.f, 0.f, 0.f, 0.f};
    float lacc[4] = {0.f, 0.f, 0.f, 0.f};
    const int skey = t & 63, sdg = t >> 6;
    _Float16* Pw = &Pt[wave][0];

    for (int kt = 0; kt < L_ / 64; ++kt) {
        __syncthreads();
        {
            const float4* kg4 = (const float4*)(K + boff + (size_t)(kt * 64 + skey) * D_ + sdg * 16);
            const float4 f0 = kg4[0], f1 = kg4[1], f2 = kg4[2], f3 = kg4[3];
            half8_t w0, w1;
            w0[0] = (_Float16)f0.x; w0[1] = (_Float16)f0.y;
            w0[2] = (_Float16)f0.z; w0[3] = (_Float16)f0.w;
            w0[4] = (_Float16)f1.x; w0[5] = (_Float16)f1.y;
            w0[6] = (_Float16)f1.z; w0[7] = (_Float16)f1.w;
            w1[0] = (_Float16)f2.x; w1[1] = (_Float16)f2.y;
            w1[2] = (_Float16)f2.z; w1[3] = (_Float16)f2.w;
            w1[4] = (_Float16)f3.x; w1[5] = (_Float16)f3.y;
            w1[6] = (_Float16)f3.z; w1[7] = (_Float16)f3.w;
            *(half8_t*)&Kt[skey * KS + sdg * 16] = w0;
            *(half8_t*)&Kt[skey * KS + sdg * 16 + 8] = w1;
        }
        {
            const float4* vg4 = (const float4*)(V + boff + (size_t)(kt * 64 + skey) * D_ + sdg * 16);
            #pragma unroll
            for (int i = 0; i < 4; ++i) {
                const float4 f = vg4[i];
                const int d0 = sdg * 16 + i * 4;
                Vt[(d0 + 0) * KS + skey] = (_Float16)f.x;
                Vt[(d0 + 1) * KS + skey] = (_Float16)f.y;
                Vt[(d0 + 2) * KS + skey] = (_Float16)f.z;
                Vt[(d0 + 3) * KS + skey] = (_Float16)f.w;
            }
        }
        __syncthreads();
        #pragma unroll
        for (int s = 0; s < 4; ++s) {
            const half8_t bk0 = *(const half8_t*)&Kt[(s * 16 + l15) * KS + quad * 8];
            const half8_t bk1 = *(const half8_t*)&Kt[(s * 16 + l15) * KS + 32 + quad * 8];
            f32x4 sc = (f32x4){0.f, 0.f, 0.f, 0.f};
            sc = __builtin_amdgcn_mfma_f32_16x16x32_f16(aq[0], bk0, sc, 0, 0, 0);
            sc = __builtin_amdgcn_mfma_f32_16x16x32_f16(aq[1], bk1, sc, 0, 0, 0);
            #pragma unroll
            for (int r = 0; r < 4; ++r) {
                const float p = __expf(sc[r] * 0.125f);
                lacc[r] += p;
                Pw[(quad * 4 + r) * KS + s * 16 + l15] = (_Float16)p;
            }
        }
        __syncthreads();
        #pragma unroll
        for (int c = 0; c < 2; ++c) {
            const half8_t ap = *(const half8_t*)&Pw[l15 * KS + c * 32 + quad * 8];
            #pragma unroll
            for (int d = 0; d < 4; ++d) {
                const half8_t bv = *(const half8_t*)&Vt[(d * 16 + l15) * KS + c * 32 + quad * 8];
                ofr[d] = __builtin_amdgcn_mfma_f32_16x16x32_f16(ap, bv, ofr[d], 0, 0, 0);
            }
        }
    }
    #pragma unroll
    for (int r = 0; r < 4; ++r) {
        float v = lacc[r];
        v += __shfl_xor(v, 1, 64);
        v += __shfl_xor(v, 2, 64);
        v += __shfl_xor(v, 4, 64);
        v += __shfl_xor(v, 8, 64);
        lacc[r] = v;
    }
    #pragma unroll
    for (int r = 0; r < 4; ++r) {
        const float inv = 1.0f / lacc[r];
        float* orow = O + boff + (size_t)(qb + quad * 4 + r) * D_ + l15;
        #pragma unroll
        for (int d = 0; d < 4; ++d) orow[d * 16] = ofr[d][r] * inv;
    }
}

extern "C" void kernel_launch(void* const* d_in, const int* in_sizes, int n_in,
                              void* d_out, int out_size, void* d_ws, size_t ws_size,
                              hipStream_t stream) {
    const float* Q = (const float*)d_in[0];
    const float* K = (const float*)d_in[1];
    const float* V = (const float*)d_in[2];
    float* O = (float*)d_out;

    if (ws_size >= (size_t)8 * 1024 * 1024) {
        _Float16* K16F  = (_Float16*)d_ws;                             // 2 MB
        _Float16* VT16F = K16F + (size_t)1048576;                      // 2 MB
        prepass_frag<<<1024, NT, 0, stream>>>(K, V, K16F, VT16F);
        attn_q64w16<<<256, 1024, 0, stream>>>(Q, K16F, VT16F, O);
    } else {
        attn_mfma_f16<<<256, NT, 0, stream>>>(Q, K, V, O);
    }
}